// Round 2
// baseline (273.844 us; speedup 1.0000x reference)
//
#include <hip/hip_runtime.h>

// Problem constants (from reference): B,T,L,R,E,F
#define B_ 8
#define T_ 16
#define L_ 128
#define R_ 1024
#define E_ 5
#define F_ 512

typedef short short8 __attribute__((ext_vector_type(8)));
typedef float floatx4 __attribute__((ext_vector_type(4)));

// fp32 -> bf16 bits, round-half-up (matches previously verified kernel)
__device__ __forceinline__ unsigned short f2bf(float f) {
  unsigned u = __float_as_uint(f);
  return (unsigned short)((u + 0x8000u) >> 16);
}

__device__ __forceinline__ short8 pack8(floatx4 lo, floatx4 hi) {
  short8 v;
  v[0] = (short)f2bf(lo[0]); v[1] = (short)f2bf(lo[1]);
  v[2] = (short)f2bf(lo[2]); v[3] = (short)f2bf(lo[3]);
  v[4] = (short)f2bf(hi[0]); v[5] = (short)f2bf(hi[1]);
  v[6] = (short)f2bf(hi[2]); v[7] = (short)f2bf(hi[3]);
  return v;
}

// async 16B global->LDS DMA; lane i's data lands at ldsbase + i*16
__device__ __forceinline__ void stage16(const float* g, float* lds) {
  __builtin_amdgcn_global_load_lds(
      (const __attribute__((address_space(1))) void*)g,
      (__attribute__((address_space(3))) void*)lds, 16, 0, 0);
}

// s_waitcnt immediates (gfx9 encoding): lgkmcnt=15 (don't care), expcnt=7,
// vmcnt in bits [3:0]
#define WAITCNT_VM9 0xF79   // vmcnt(9): chunks g+1..g+3 (3 DMA each) in flight
#define WAITCNT_VM6 0xF76
#define WAITCNT_VM3 0xF73
#define WAITCNT_VM0 0xF70

// ---------------------------------------------------------------------------
// Kernel 1: rot = QR(pre_rot).Q (LAPACK Householder convention), then
// new_lig[b,t,l,:] = rot[b,t] @ lig_coord[b,l] + trans[b,t].
// Also zeroes out[bt] so the fused kernel can atomicAdd.
// ---------------------------------------------------------------------------
__global__ void prep_kernel(const float* __restrict__ lig_coord,
                            const float* __restrict__ pre_rot,
                            const float* __restrict__ trans,
                            float* __restrict__ new_lig,
                            float* __restrict__ out) {
  int bt = blockIdx.x;
  __shared__ float Qs[3][3];
  if (threadIdx.x == 0) {
    out[bt] = 0.f;                      // zero output for atomic accumulation
    float a[3][3], q[3][3];
    #pragma unroll
    for (int i = 0; i < 3; ++i)
      #pragma unroll
      for (int j = 0; j < 3; ++j) {
        a[i][j] = pre_rot[(bt * 3 + i) * 3 + j];
        q[i][j] = (i == j) ? 1.f : 0.f;
      }
    for (int k = 0; k < 3; ++k) {
      float alpha = a[k][k];
      float xn2 = 0.f;
      for (int i = k + 1; i < 3; ++i) xn2 += a[i][k] * a[i][k];
      float nrm = sqrtf(alpha * alpha + xn2);
      if (xn2 > 0.f && nrm > 0.f) {
        float beta = (alpha >= 0.f) ? -nrm : nrm;
        float tau = (beta - alpha) / beta;
        float inv = 1.f / (alpha - beta);
        float v[3] = {0.f, 0.f, 0.f};
        v[k] = 1.f;
        for (int i = k + 1; i < 3; ++i) v[i] = a[i][k] * inv;
        for (int j = k; j < 3; ++j) {
          float w = 0.f;
          for (int i = k; i < 3; ++i) w += v[i] * a[i][j];
          w *= tau;
          for (int i = k; i < 3; ++i) a[i][j] -= w * v[i];
        }
        for (int i = 0; i < 3; ++i) {
          float w = 0.f;
          for (int j = k; j < 3; ++j) w += q[i][j] * v[j];
          w *= tau;
          for (int j = k; j < 3; ++j) q[i][j] -= w * v[j];
        }
      }
    }
    for (int i = 0; i < 3; ++i)
      for (int j = 0; j < 3; ++j) Qs[i][j] = q[i][j];
  }
  __syncthreads();
  int b = bt >> 4;
  int l = threadIdx.x;
  float cx = lig_coord[(b * L_ + l) * 3 + 0];
  float cy = lig_coord[(b * L_ + l) * 3 + 1];
  float cz = lig_coord[(b * L_ + l) * 3 + 2];
  float nx = Qs[0][0] * cx + Qs[0][1] * cy + Qs[0][2] * cz + trans[bt * 3 + 0];
  float ny = Qs[1][0] * cx + Qs[1][1] * cy + Qs[1][2] * cz + trans[bt * 3 + 1];
  float nz = Qs[2][0] * cx + Qs[2][1] * cy + Qs[2][2] * cz + trans[bt * 3 + 2];
  float* o = new_lig + ((size_t)bt * L_ + l) * 3;
  o[0] = nx; o[1] = ny; o[2] = nz;
}

// ---------------------------------------------------------------------------
// Kernel 2 (fused): per block (r-tile 32, m-tile 64, b):
//  Phase A: GEMM acc[e][m][n] = sum_f lig[b,m,e,f]*rec[b,r0+n,e,f] as ONE
//           80-chunk K-sweep ((e,f) contiguous), depth-3 prefetch across
//           4 LDS buffers (vmcnt(9) steady state), 5 e-accs in registers.
//  Phase B: mask acc by (m<ligN && r<recN); distance/power phase straight
//           from the MFMA C-fragment layout; block-reduce U[16]; atomicAdd.
// Tile: M=64 x N=32, 4 waves (wave tile 16x32), BK=32 f32.
// Grid 512 blocks -> 2-3 resident blocks/CU (latency cover across barriers).
// ---------------------------------------------------------------------------
__launch_bounds__(256)
__global__ void fused_kernel(const float* __restrict__ lig_feat,
                             const float* __restrict__ rec_feat,
                             const float* __restrict__ rec_coord,
                             const int* __restrict__ lig_counts,
                             const int* __restrict__ rec_counts,
                             const float* __restrict__ new_lig,
                             float* __restrict__ out) {
  const int rt = blockIdx.x;          // 0..31
  const int mt = blockIdx.y;          // 0..1
  const int b  = blockIdx.z;          // 0..7
  const int r0 = rt * 32;
  const int recN = rec_counts[b];
  if (r0 >= recN) return;             // fully-masked tile contributes 0

  // 48KB arena: A 4 bufs x 64x32 f32, B 4 bufs x 32x32 f32.
  // Reused for new_lig (24KB) after GEMM.
  __shared__ __align__(16) float smem[4 * 64 * 32 + 4 * 32 * 32];
  __shared__ float smr[4][T_];
  float* const As0 = smem;                   // [4][64*32]
  float* const Bs0 = smem + 4 * 64 * 32;     // [4][32*32]

  const int tid  = threadIdx.x;
  const int wave = tid >> 6;
  const int lane = tid & 63;
  const int lrow = lane & 15;
  const int quad = lane >> 4;
  const int wm   = wave * 16;

  // staging: each wave stages 2x8 A-rows + 1x8 B-rows (3 DMA/chunk, uniform).
  // 16B-chunk swizzle applied on the GLOBAL side (DMA LDS dst is linear).
  const int lr8 = lane >> 3;
  const int sw  = (lane & 7) ^ lr8;

  const float* ga0 = lig_feat +
      ((size_t)(b * L_ + mt * 64 + wave * 16 + 0 + lr8) * E_) * F_ + sw * 4;
  const float* ga1 = lig_feat +
      ((size_t)(b * L_ + mt * 64 + wave * 16 + 8 + lr8) * E_) * F_ + sw * 4;
  const float* gb = rec_feat +
      ((size_t)(b * R_ + r0 + wave * 8 + lr8) * E_) * F_ + sw * 4;

  const int dstA0 = (wave * 16 + 0) * 32;
  const int dstA1 = (wave * 16 + 8) * 32;
  const int dstB  = (wave * 8) * 32;

  floatx4 acc[E_][2];
  #pragma unroll
  for (int e = 0; e < E_; ++e)
    #pragma unroll
    for (int j = 0; j < 2; ++j)
      acc[e][j] = (floatx4){0.f, 0.f, 0.f, 0.f};

  // prologue: chunks 0,1,2 -> bufs 0,1,2 (9 DMAs per wave)
  #pragma unroll
  for (int c = 0; c < 3; ++c) {
    float* ab = As0 + c * (64 * 32);
    float* bb = Bs0 + c * (32 * 32);
    stage16(ga0 + c * 32, ab + dstA0);
    stage16(ga1 + c * 32, ab + dstA1);
    stage16(gb + c * 32, bb + dstB);
  }

  // fragment-read physical chunks (row&7 == lane&7 for all fragment rows)
  const int c0 = (2 * quad) ^ (lane & 7);

  // 80-chunk K-sweep: chunk g covers e=g>>4, f=(g&15)*32..+31 — contiguous
  // in memory; prefetch runs straight across e boundaries, depth 3.
  #pragma unroll
  for (int e = 0; e < E_; ++e) {
    #pragma unroll 1
    for (int kc = 0; kc < 16; ++kc) {
      const int g = e * 16 + kc;
      const int buf = g & 3;
      if (g > 0)
        __builtin_amdgcn_s_barrier();   // readers of buf[(g+3)&3] retired
      if (g < 77) {                     // prefetch chunk g+3
        const int c = g + 3;
        float* ab = As0 + (c & 3) * (64 * 32);
        float* bb = Bs0 + (c & 3) * (32 * 32);
        stage16(ga0 + c * 32, ab + dstA0);
        stage16(ga1 + c * 32, ab + dstA1);
        stage16(gb + c * 32, bb + dstB);
        __builtin_amdgcn_s_waitcnt(WAITCNT_VM9);  // chunk g landed; 9 in flight
      } else if (g == 77) {
        __builtin_amdgcn_s_waitcnt(WAITCNT_VM6);
      } else if (g == 78) {
        __builtin_amdgcn_s_waitcnt(WAITCNT_VM3);
      } else {
        __builtin_amdgcn_s_waitcnt(WAITCNT_VM0);
      }
      __builtin_amdgcn_s_barrier();     // every wave's chunk-g stage landed
      __builtin_amdgcn_sched_barrier(0);

      const float* abase = As0 + buf * (64 * 32) + (wm + lrow) * 32;
      short8 af = pack8(*(const floatx4*)(abase + c0 * 4),
                        *(const floatx4*)(abase + (c0 ^ 1) * 4));
      const float* bbase0 = Bs0 + buf * (32 * 32) + lrow * 32;
      const float* bbase1 = Bs0 + buf * (32 * 32) + (16 + lrow) * 32;
      short8 bf0 = pack8(*(const floatx4*)(bbase0 + c0 * 4),
                         *(const floatx4*)(bbase0 + (c0 ^ 1) * 4));
      short8 bf1 = pack8(*(const floatx4*)(bbase1 + c0 * 4),
                         *(const floatx4*)(bbase1 + (c0 ^ 1) * 4));
      acc[e][0] = __builtin_amdgcn_mfma_f32_16x16x32_bf16(af, bf0, acc[e][0], 0, 0, 0);
      acc[e][1] = __builtin_amdgcn_mfma_f32_16x16x32_bf16(af, bf1, acc[e][1], 0, 0, 0);
    }
  }

  __syncthreads();                      // GEMM LDS traffic fully retired

  // ---- Phase B: distance/power, atn consumed straight from C-fragments ----
  // C layout (verified): m = mt*64 + wm + quad*4 + reg, n = j*16 + lrow.

  // stage new_lig[b] ([T,L,3] = 24KB) into reused staging LDS
  float* const nlp = smem;
  {
    const floatx4* src = (const floatx4*)(new_lig + (size_t)b * T_ * L_ * 3);
    floatx4* dst = (floatx4*)nlp;       // 6144 floats = 1536 float4
    #pragma unroll
    for (int i = 0; i < 6; ++i) dst[tid + i * 256] = src[tid + i * 256];
  }
  __syncthreads();

  // pair mask applied ONCE by zeroing acc registers (distance loop unmasked)
  const int ligN = lig_counts[b];
  #pragma unroll
  for (int j = 0; j < 2; ++j) {
    const bool nv = (r0 + j * 16 + lrow) < recN;
    #pragma unroll
    for (int reg = 0; reg < 4; ++reg) {
      const bool mv = (mt * 64 + wm + quad * 4 + reg) < ligN;
      if (!(nv && mv)) {
        #pragma unroll
        for (int e = 0; e < E_; ++e) acc[e][j][reg] = 0.f;
      }
    }
  }

  float rcx[2], rcy[2], rcz[2];
  #pragma unroll
  for (int j = 0; j < 2; ++j) {
    const float* rp = rec_coord + (size_t)(b * R_ + r0 + j * 16 + lrow) * 3;
    rcx[j] = rp[0]; rcy[j] = rp[1]; rcz[j] = rp[2];
  }

  float u[T_];
  #pragma unroll
  for (int t = 0; t < T_; ++t) u[t] = 0.f;

  #pragma unroll
  for (int t = 0; t < T_; ++t) {        // full unroll: u[t] stays in regs
    float nx[4], ny[4], nz[4];
    #pragma unroll
    for (int reg = 0; reg < 4; ++reg) { // quad-uniform -> LDS broadcast
      const float* np = nlp + ((t * L_) + mt * 64 + wm + quad * 4 + reg) * 3;
      nx[reg] = np[0]; ny[reg] = np[1]; nz[reg] = np[2];
    }
    #pragma unroll
    for (int j = 0; j < 2; ++j)
      #pragma unroll
      for (int reg = 0; reg < 4; ++reg) {
        float dx = nx[reg] - rcx[j];
        float dy = ny[reg] - rcy[j];
        float dz = nz[reg] - rcz[j];
        float d2 = fmaf(dx, dx, fmaf(dy, dy, dz * dz));
        d2 = fmaxf(d2, 1e-20f);
        float rs  = rsqrtf(d2);         // exps [-3,-2,-1,1,2]
        float rs2 = rs * rs;
        float rs3 = rs2 * rs;
        float d1  = d2 * rs;
        float c = acc[0][j][reg] * rs3;
        c = fmaf(acc[1][j][reg], rs2, c);
        c = fmaf(acc[2][j][reg], rs,  c);
        c = fmaf(acc[3][j][reg], d1,  c);
        c = fmaf(acc[4][j][reg], d2,  c);
        u[t] += c;
      }
  }

  // block-reduce U[16] and accumulate
  #pragma unroll
  for (int t = 0; t < T_; ++t) {
    float v = u[t];
    #pragma unroll
    for (int m = 32; m > 0; m >>= 1) v += __shfl_xor(v, m, 64);
    if (lane == 0) smr[wave][t] = v;
  }
  __syncthreads();
  if (tid < T_) {
    float s = smr[0][tid] + smr[1][tid] + smr[2][tid] + smr[3][tid];
    atomicAdd(&out[b * T_ + tid], s);
  }
}

// ---------------------------------------------------------------------------
extern "C" void kernel_launch(void* const* d_in, const int* in_sizes, int n_in,
                              void* d_out, int out_size, void* d_ws, size_t ws_size,
                              hipStream_t stream) {
  const float* lig_feat   = (const float*)d_in[0];
  const float* rec_feat   = (const float*)d_in[1];
  const float* lig_coord  = (const float*)d_in[2];
  const float* rec_coord  = (const float*)d_in[3];
  const float* pre_rot    = (const float*)d_in[4];
  const float* trans      = (const float*)d_in[5];
  const int*   lig_counts = (const int*)d_in[6];
  const int*   rec_counts = (const int*)d_in[7];
  float* out = (float*)d_out;

  // ws: new_lig [B,T,L,3] f32 (196KB) — only intermediate that remains
  float* new_lig = (float*)d_ws;

  prep_kernel<<<dim3(B_ * T_), dim3(L_), 0, stream>>>(lig_coord, pre_rot, trans,
                                                      new_lig, out);
  fused_kernel<<<dim3(R_ / 32, 2, B_), dim3(256), 0, stream>>>(
      lig_feat, rec_feat, rec_coord, lig_counts, rec_counts, new_lig, out);
}

// Round 3
// 180.482 us; speedup vs baseline: 1.5173x; 1.5173x over previous
//
#include <hip/hip_runtime.h>

// Problem constants (from reference): B,T,L,R,E,F
#define B_ 8
#define T_ 16
#define L_ 128
#define R_ 1024
#define E_ 5
#define F_ 512

typedef short short8 __attribute__((ext_vector_type(8)));
typedef float floatx4 __attribute__((ext_vector_type(4)));

// fp32 -> bf16 bits, round-half-up (matches previously verified kernel)
__device__ __forceinline__ unsigned short f2bf(float f) {
  unsigned u = __float_as_uint(f);
  return (unsigned short)((u + 0x8000u) >> 16);
}

__device__ __forceinline__ short8 pack8(floatx4 lo, floatx4 hi) {
  short8 v;
  v[0] = (short)f2bf(lo[0]); v[1] = (short)f2bf(lo[1]);
  v[2] = (short)f2bf(lo[2]); v[3] = (short)f2bf(lo[3]);
  v[4] = (short)f2bf(hi[0]); v[5] = (short)f2bf(hi[1]);
  v[6] = (short)f2bf(hi[2]); v[7] = (short)f2bf(hi[3]);
  return v;
}

// async 16B global->LDS DMA; lane i's data lands at ldsbase + i*16
__device__ __forceinline__ void stage16(const float* g, float* lds) {
  __builtin_amdgcn_global_load_lds(
      (const __attribute__((address_space(1))) void*)g,
      (__attribute__((address_space(3))) void*)lds, 16, 0, 0);
}

// s_waitcnt immediates (gfx9 encoding): lgkmcnt=15 (don't care), expcnt=7,
// vmcnt in bits [3:0]
#define WAITCNT_VM6 0xF76   // vmcnt(6): current chunk's 6 DMAs done, 6 newer in flight
#define WAITCNT_VM0 0xF70   // vmcnt(0)

// ---------------------------------------------------------------------------
// Kernel 1: rot = QR(pre_rot).Q (LAPACK Householder convention), then
// new_lig[b,t,l,:] = rot[b,t] @ lig_coord[b,l] + trans[b,t].
// Also zeroes out[bt] so the fused kernel can atomicAdd.
// ---------------------------------------------------------------------------
__global__ void prep_kernel(const float* __restrict__ lig_coord,
                            const float* __restrict__ pre_rot,
                            const float* __restrict__ trans,
                            float* __restrict__ new_lig,
                            float* __restrict__ out) {
  int bt = blockIdx.x;
  __shared__ float Qs[3][3];
  if (threadIdx.x == 0) {
    out[bt] = 0.f;                      // zero output for atomic accumulation
    float a[3][3], q[3][3];
    #pragma unroll
    for (int i = 0; i < 3; ++i)
      #pragma unroll
      for (int j = 0; j < 3; ++j) {
        a[i][j] = pre_rot[(bt * 3 + i) * 3 + j];
        q[i][j] = (i == j) ? 1.f : 0.f;
      }
    for (int k = 0; k < 3; ++k) {
      float alpha = a[k][k];
      float xn2 = 0.f;
      for (int i = k + 1; i < 3; ++i) xn2 += a[i][k] * a[i][k];
      float nrm = sqrtf(alpha * alpha + xn2);
      if (xn2 > 0.f && nrm > 0.f) {
        float beta = (alpha >= 0.f) ? -nrm : nrm;
        float tau = (beta - alpha) / beta;
        float inv = 1.f / (alpha - beta);
        float v[3] = {0.f, 0.f, 0.f};
        v[k] = 1.f;
        for (int i = k + 1; i < 3; ++i) v[i] = a[i][k] * inv;
        for (int j = k; j < 3; ++j) {
          float w = 0.f;
          for (int i = k; i < 3; ++i) w += v[i] * a[i][j];
          w *= tau;
          for (int i = k; i < 3; ++i) a[i][j] -= w * v[i];
        }
        for (int i = 0; i < 3; ++i) {
          float w = 0.f;
          for (int j = k; j < 3; ++j) w += q[i][j] * v[j];
          w *= tau;
          for (int j = k; j < 3; ++j) q[i][j] -= w * v[j];
        }
      }
    }
    for (int i = 0; i < 3; ++i)
      for (int j = 0; j < 3; ++j) Qs[i][j] = q[i][j];
  }
  __syncthreads();
  int b = bt >> 4;
  int l = threadIdx.x;
  float cx = lig_coord[(b * L_ + l) * 3 + 0];
  float cy = lig_coord[(b * L_ + l) * 3 + 1];
  float cz = lig_coord[(b * L_ + l) * 3 + 2];
  float nx = Qs[0][0] * cx + Qs[0][1] * cy + Qs[0][2] * cz + trans[bt * 3 + 0];
  float ny = Qs[1][0] * cx + Qs[1][1] * cy + Qs[1][2] * cz + trans[bt * 3 + 1];
  float nz = Qs[2][0] * cx + Qs[2][1] * cy + Qs[2][2] * cz + trans[bt * 3 + 2];
  float* o = new_lig + ((size_t)bt * L_ + l) * 3;
  o[0] = nx; o[1] = ny; o[2] = nz;
}

// ---------------------------------------------------------------------------
// Phase B (templated on e-index): U[t] += sum_pairs acc * d^exp[e].
// exps = [-3,-2,-1,1,2] -> specialized power ladder (0-3 ops from rsqrt).
// t-loop rolled x4 (inner 4 unrolled); wave-reduce each t into smr[wave][t].
// ---------------------------------------------------------------------------
template <int EIDX>
__device__ __forceinline__ void phaseB(const floatx4 (&acc)[2][4],
                                       const float* nlp,
                                       const float (&rcx)[4],
                                       const float (&rcy)[4],
                                       const float (&rcz)[4],
                                       int wm, int quad, int lane, int wave,
                                       float (*smr)[T_]) {
  #pragma unroll 1
  for (int tg = 0; tg < 4; ++tg) {
    #pragma unroll
    for (int it = 0; it < 4; ++it) {
      const int t = tg * 4 + it;
      float uacc = 0.f;
      #pragma unroll
      for (int i = 0; i < 2; ++i)
        #pragma unroll
        for (int reg = 0; reg < 4; ++reg) {
          const int m = wm + i * 16 + quad * 4 + reg;
          const float* np = nlp + (t * L_ + m) * 3;   // quad-uniform: broadcast
          const float nx = np[0], ny = np[1], nz = np[2];
          #pragma unroll
          for (int j = 0; j < 4; ++j) {
            float dx = nx - rcx[j];
            float dy = ny - rcy[j];
            float dz = nz - rcz[j];
            float d2 = fmaf(dx, dx, fmaf(dy, dy, dz * dz));
            d2 = fmaxf(d2, 1e-20f);
            float p;
            if constexpr (EIDX == 0) {        // d^-3
              float rs = rsqrtf(d2); p = rs * rs * rs;
            } else if constexpr (EIDX == 1) { // d^-2
              float rs = rsqrtf(d2); p = rs * rs;
            } else if constexpr (EIDX == 2) { // d^-1
              p = rsqrtf(d2);
            } else if constexpr (EIDX == 3) { // d^1
              float rs = rsqrtf(d2); p = d2 * rs;
            } else {                          // d^2
              p = d2;
            }
            uacc = fmaf(acc[i][j][reg], p, uacc);
          }
        }
      #pragma unroll
      for (int m_ = 32; m_ > 0; m_ >>= 1) uacc += __shfl_xor(uacc, m_, 64);
      if (lane == 0) smr[wave][t] = uacc;
    }
    __syncthreads();  // smr[..][tg*4..tg*4+3] complete before next group reuses
  }
}

// ---------------------------------------------------------------------------
// Kernel 2 (fused-by-e): grid (16 rt, 5 e, 8 b) = 640 blocks, 256 threads.
//  Phase A: EXACT round-0 gemm mainloop (M=128 x N=64, wave tile 32x64,
//           8 MFMA/chunk, BK=32, dbuf, vmcnt(6) fine sync) for this block's e.
//  Phase B: mask acc, distance/power phase (e-specialized), wave-reduce,
//           atomicAdd into out. atn never touches memory.
// ---------------------------------------------------------------------------
__launch_bounds__(256)
__global__ void fused_kernel(const float* __restrict__ lig_feat,
                             const float* __restrict__ rec_feat,
                             const float* __restrict__ rec_coord,
                             const int* __restrict__ lig_counts,
                             const int* __restrict__ rec_counts,
                             const float* __restrict__ new_lig,
                             float* __restrict__ out) {
  const int rt = blockIdx.x;    // 0..15
  const int e  = blockIdx.y;    // 0..4
  const int b  = blockIdx.z;    // 0..7
  const int r0 = rt * 64;
  const int recN = rec_counts[b];
  if (r0 >= recN) return;       // fully-masked tile contributes 0

  __shared__ __align__(16) float As[2][128 * 32];  // 32KB (aliased by nl later)
  __shared__ __align__(16) float Bs[2][64 * 32];   // 16KB
  __shared__ float smr[4][T_];

  const int tid  = threadIdx.x;
  const int wave = tid >> 6;
  const int lane = tid & 63;
  const int lrow = lane & 15;
  const int quad = lane >> 4;
  const int wm   = wave * 32;

  // staging: wave stages 8 rows/instr; 16B-chunk swizzled on the GLOBAL
  // side (chunk ^= row&7) since the DMA's LDS dst is linear base+lane*16.
  const int lr8 = lane >> 3;
  const int sw  = (lane & 7) ^ lr8;
  const float* ga[4];
  #pragma unroll
  for (int i = 0; i < 4; ++i) {
    int row = wave * 32 + i * 8 + lr8;
    ga[i] = lig_feat + ((size_t)(b * L_ + row) * E_ + e) * F_ + sw * 4;
  }
  const float* gb[2];
  #pragma unroll
  for (int i = 0; i < 2; ++i) {
    int row = wave * 16 + i * 8 + lr8;
    gb[i] = rec_feat + ((size_t)(b * R_ + r0 + row) * E_ + e) * F_ + sw * 4;
  }

  floatx4 acc[2][4];
  #pragma unroll
  for (int i = 0; i < 2; ++i)
    #pragma unroll
    for (int j = 0; j < 4; ++j)
      acc[i][j] = (floatx4){0.f, 0.f, 0.f, 0.f};

  // fragment-read physical chunks (row&7 == lane&7 for all fragment rows)
  const int c0 = (2 * quad) ^ (lane & 7);

  // stage chunk 0 -> buf 0 (6 DMA loads per wave)
  #pragma unroll
  for (int i = 0; i < 4; ++i) stage16(ga[i], &As[0][(wave * 32 + i * 8) * 32]);
  #pragma unroll
  for (int i = 0; i < 2; ++i) stage16(gb[i], &Bs[0][(wave * 16 + i * 8) * 32]);

  #pragma unroll 1
  for (int kc = 0; kc < 16; ++kc) {
    const int cur = kc & 1;
    if (kc > 0)
      __builtin_amdgcn_s_barrier();     // all waves done reading buf[cur^1]
    if (kc < 15) {                      // prefetch next chunk -> buf[cur^1]
      const int col = (kc + 1) * 32;
      #pragma unroll
      for (int i = 0; i < 4; ++i)
        stage16(ga[i] + col, &As[cur ^ 1][(wave * 32 + i * 8) * 32]);
      #pragma unroll
      for (int i = 0; i < 2; ++i)
        stage16(gb[i] + col, &Bs[cur ^ 1][(wave * 16 + i * 8) * 32]);
      __builtin_amdgcn_s_waitcnt(WAITCNT_VM6);  // stage(kc) done; 6 in flight
    } else {
      __builtin_amdgcn_s_waitcnt(WAITCNT_VM0);
    }
    __builtin_amdgcn_s_barrier();       // every wave's stage(kc) landed
    __builtin_amdgcn_sched_barrier(0);  // keep ds_reads below the barrier

    short8 af[2], bfv[4];
    #pragma unroll
    for (int i = 0; i < 2; ++i) {
      const float* base = &As[cur][(wm + i * 16 + lrow) * 32];
      af[i] = pack8(*(const floatx4*)(base + c0 * 4),
                    *(const floatx4*)(base + (c0 ^ 1) * 4));
    }
    #pragma unroll
    for (int j = 0; j < 4; ++j) {
      const float* base = &Bs[cur][(j * 16 + lrow) * 32];
      bfv[j] = pack8(*(const floatx4*)(base + c0 * 4),
                     *(const floatx4*)(base + (c0 ^ 1) * 4));
    }
    #pragma unroll
    for (int i = 0; i < 2; ++i)
      #pragma unroll
      for (int j = 0; j < 4; ++j)
        acc[i][j] = __builtin_amdgcn_mfma_f32_16x16x32_bf16(af[i], bfv[j], acc[i][j], 0, 0, 0);
  }

  __syncthreads();                      // GEMM LDS reads fully retired

  // ---- Phase B: distance/power straight from the C-fragment layout ----
  // C layout (verified): m = wm + i*16 + quad*4 + reg, n = j*16 + lrow.

  // stage new_lig[b] ([T,L,3] = 24KB) into reused As
  float* const nlp = &As[0][0];
  {
    const floatx4* src = (const floatx4*)(new_lig + (size_t)b * T_ * L_ * 3);
    floatx4* dst = (floatx4*)nlp;       // 6144 floats = 1536 float4
    #pragma unroll
    for (int i = 0; i < 6; ++i) dst[tid + i * 256] = src[tid + i * 256];
  }
  __syncthreads();

  // pair mask applied ONCE by zeroing acc registers (distance loop unmasked)
  const int ligN = lig_counts[b];
  #pragma unroll
  for (int j = 0; j < 4; ++j) {
    const bool nv = (r0 + j * 16 + lrow) < recN;
    #pragma unroll
    for (int i = 0; i < 2; ++i)
      #pragma unroll
      for (int reg = 0; reg < 4; ++reg) {
        const bool mv = (wm + i * 16 + quad * 4 + reg) < ligN;
        if (!(nv && mv)) acc[i][j][reg] = 0.f;
      }
  }

  float rcx[4], rcy[4], rcz[4];
  #pragma unroll
  for (int j = 0; j < 4; ++j) {
    const float* rp = rec_coord + (size_t)(b * R_ + r0 + j * 16 + lrow) * 3;
    rcx[j] = rp[0]; rcy[j] = rp[1]; rcz[j] = rp[2];
  }

  if (e == 0)      phaseB<0>(acc, nlp, rcx, rcy, rcz, wm, quad, lane, wave, smr);
  else if (e == 1) phaseB<1>(acc, nlp, rcx, rcy, rcz, wm, quad, lane, wave, smr);
  else if (e == 2) phaseB<2>(acc, nlp, rcx, rcy, rcz, wm, quad, lane, wave, smr);
  else if (e == 3) phaseB<3>(acc, nlp, rcx, rcy, rcz, wm, quad, lane, wave, smr);
  else             phaseB<4>(acc, nlp, rcx, rcy, rcz, wm, quad, lane, wave, smr);

  __syncthreads();
  if (tid < T_) {
    float s = smr[0][tid] + smr[1][tid] + smr[2][tid] + smr[3][tid];
    atomicAdd(&out[b * T_ + tid], s);
  }
}

// ---------------------------------------------------------------------------
extern "C" void kernel_launch(void* const* d_in, const int* in_sizes, int n_in,
                              void* d_out, int out_size, void* d_ws, size_t ws_size,
                              hipStream_t stream) {
  const float* lig_feat   = (const float*)d_in[0];
  const float* rec_feat   = (const float*)d_in[1];
  const float* lig_coord  = (const float*)d_in[2];
  const float* rec_coord  = (const float*)d_in[3];
  const float* pre_rot    = (const float*)d_in[4];
  const float* trans      = (const float*)d_in[5];
  const int*   lig_counts = (const int*)d_in[6];
  const int*   rec_counts = (const int*)d_in[7];
  float* out = (float*)d_out;

  // ws: new_lig [B,T,L,3] f32 (196KB) — only intermediate that remains
  float* new_lig = (float*)d_ws;

  prep_kernel<<<dim3(B_ * T_), dim3(L_), 0, stream>>>(lig_coord, pre_rot, trans,
                                                      new_lig, out);
  fused_kernel<<<dim3(R_ / 64, E_, B_), dim3(256), 0, stream>>>(
      lig_feat, rec_feat, rec_coord, lig_counts, rec_counts, new_lig, out);
}